// Round 4
// baseline (270.486 us; speedup 1.0000x reference)
//
#include <hip/hip_runtime.h>
#include <stdint.h>
#include <math.h>

#define NH 16
#define DK 64
#define S_LEN 2048
#define BB 4
#define DM 1024
#define M_TOT (BB*S_LEN) // 8192
#define KVT 64
#define KPAD 72
#define QB 128

// ---- GEMM geometry: 256x128 tile, BK=64, 8 waves (4M x 2N), triple-buffered LDS ----
#define BM 256
#define BN 128
#define BK 64
#define NTK (DM/BK)            // 16 K-tiles
#define LDS_A_BUF (BM*BK)      // 16384 ushort per buffer
#define LDS_B_BUF (BN*BK)      // 8192 ushort per buffer

typedef __attribute__((ext_vector_type(8))) short short8;
typedef __attribute__((ext_vector_type(4))) float floatx4;

typedef const __attribute__((address_space(1))) void gas_t;
typedef __attribute__((address_space(3))) void las_t;

__device__ __forceinline__ void glds16(const void* g, void* l){
  __builtin_amdgcn_global_load_lds((gas_t*)g, (las_t*)l, 16, 0, 0);
}

// Sync primitives: inline-asm with "memory" clobber = compiler fence too.
#define VMCNT3() asm volatile("s_waitcnt vmcnt(3)" ::: "memory")
#define VMCNT6() asm volatile("s_waitcnt vmcnt(6)" ::: "memory")
#define VMCNT0() asm volatile("s_waitcnt vmcnt(0)" ::: "memory")
#define LGKM0()  do{ asm volatile("s_waitcnt lgkmcnt(0)" ::: "memory"); __builtin_amdgcn_sched_barrier(0); }while(0)
#define BARRIER() asm volatile("s_barrier" ::: "memory")
#define SCHEDB() __builtin_amdgcn_sched_barrier(0)

__device__ __forceinline__ unsigned short f2bf(float f){
  unsigned int u = __float_as_uint(f);
  u += 0x7fffu + ((u >> 16) & 1u);
  return (unsigned short)(u >> 16);
}
// pack hi16(b):hi16(a) in one v_perm_b32 (truncation-rounded bf16 pair; a = low half)
__device__ __forceinline__ unsigned int pk_bf_trunc(float a, float b){
  return __builtin_amdgcn_perm(__float_as_uint(b), __float_as_uint(a), 0x07060302u);
}
__device__ __forceinline__ float fast_exp2(float x){
  return __builtin_amdgcn_exp2f(x);
}

// ---------------- cast fp32 -> bf16 ----------------
__global__ void cast_kernel(const float* __restrict__ in, unsigned short* __restrict__ out, int n){
  int i = (blockIdx.x * blockDim.x + threadIdx.x) * 4;
  if (i < n){
    float4 v = *(const float4*)(in + i);
    ushort4 u;
    u.x = f2bf(v.x); u.y = f2bf(v.y); u.z = f2bf(v.z); u.w = f2bf(v.w);
    *(ushort4*)(out + i) = u;
  }
}
// 4 weight matrices in one launch (blockIdx.y selects)
__global__ void cast4_kernel(const float* __restrict__ a, const float* __restrict__ b,
                             const float* __restrict__ c, const float* __restrict__ d,
                             unsigned short* __restrict__ oa, unsigned short* __restrict__ ob,
                             unsigned short* __restrict__ oc, unsigned short* __restrict__ od){
  int z = blockIdx.y;
  const float* s = (z==0)?a:(z==1)?b:(z==2)?c:d;
  unsigned short* o = (z==0)?oa:(z==1)?ob:(z==2)?oc:od;
  int i = (blockIdx.x * blockDim.x + threadIdx.x) * 4;
  float4 v = *(const float4*)(s + i);
  ushort4 u;
  u.x = f2bf(v.x); u.y = f2bf(v.y); u.z = f2bf(v.z); u.w = f2bf(v.w);
  *(ushort4*)(o + i) = u;
}

// Stage half of one K-tile (3 x glds16: 2 A-chunks + 1 B-chunk per thread).
// LDS dest is lane-linear (global_load_lds requirement); bank-conflict-free reads
// come from XOR-swizzling the SOURCE address: phys 16B-slot p of row r holds
// logical slot p^(r&7).  (Verified: SQ_LDS_BANK_CONFLICT == 0.)
__device__ __forceinline__ void stage_part(const unsigned short* __restrict__ A,
                                           const unsigned short* __restrict__ Bm,
                                           int m0, int n0, int k0,
                                           unsigned short* As, unsigned short* Bs,
                                           int tid, int part)
{
  if (part == 0){
    #pragma unroll
    for (int j = 0; j < 2; j++){
      int c = j*512 + tid;                 // 16B chunk index; row has 8 chunks (128B)
      int r = c >> 3;
      int sl = (c & 7) ^ (r & 7);
      glds16(&A[(size_t)(m0 + r)*DM + k0 + sl*8], (char*)As + (size_t)c*16);
    }
    int c = tid;
    int r = c >> 3;
    int sl = (c & 7) ^ (r & 7);
    glds16(&Bm[(size_t)(n0 + r)*DM + k0 + sl*8], (char*)Bs + (size_t)c*16);
  } else {
    #pragma unroll
    for (int j = 2; j < 4; j++){
      int c = j*512 + tid;
      int r = c >> 3;
      int sl = (c & 7) ^ (r & 7);
      glds16(&A[(size_t)(m0 + r)*DM + k0 + sl*8], (char*)As + (size_t)c*16);
    }
    int c = 512 + tid;
    int r = c >> 3;
    int sl = (c & 7) ^ (r & 7);
    glds16(&Bm[(size_t)(n0 + r)*DM + k0 + sl*8], (char*)Bs + (size_t)c*16);
  }
}

// Triple-buffered, counted-vmcnt, phase-interleaved K-loop with REGISTER
// SOFTWARE PIPELINING: each phase's MFMA consumes fragments ds_read a full
// phase earlier, so the 8-wave LDS read burst drains under the previous
// phase's MFMA shadow instead of serializing in front of it.
__device__ __forceinline__ void gemm_core(const unsigned short* __restrict__ A,
                                          const unsigned short* __restrict__ Bm,
                                          int m0, int n0, unsigned short* Ls,
                                          int tid, floatx4 (&acc)[4][4])
{
  unsigned short* AsB = Ls;                   // 3 x LDS_A_BUF
  unsigned short* BsB = Ls + 3*LDS_A_BUF;     // 3 x LDS_B_BUF
  int wave = tid >> 6, lane = tid & 63;
  int l15 = lane & 15, quad = lane >> 4;
  int wm = (wave >> 1) * 64, wn = (wave & 1) * 64;
  int s0 = quad ^ (l15 & 7);                  // swizzled slot for kk=0; kk=1 is s0^4

  short8 a01[2][2], a23[2][2], b[2][4][2];    // b parity-indexed (live both phases)

  // ---- prologue: stage tiles 0,1; pre-read fragsA(0)+b(0) ----
  stage_part(A, Bm, m0, n0, 0,  AsB,             BsB,             tid, 0);
  stage_part(A, Bm, m0, n0, 0,  AsB,             BsB,             tid, 1);
  stage_part(A, Bm, m0, n0, BK, AsB + LDS_A_BUF, BsB + LDS_B_BUF, tid, 0);
  stage_part(A, Bm, m0, n0, BK, AsB + LDS_A_BUF, BsB + LDS_B_BUF, tid, 1);
  VMCNT6();                                   // tile0 landed; tile1 in flight
  BARRIER();
  #pragma unroll
  for (int mi = 0; mi < 2; mi++){
    const unsigned short* pr = AsB + (wm + mi*16 + l15)*BK;
    a01[mi][0] = *(const short8*)(pr + s0*8);
    a01[mi][1] = *(const short8*)(pr + (s0^4)*8);
  }
  #pragma unroll
  for (int ni = 0; ni < 4; ni++){
    const unsigned short* pr = BsB + (wn + ni*16 + l15)*BK;
    b[0][ni][0] = *(const short8*)(pr + s0*8);
    b[0][ni][1] = *(const short8*)(pr + (s0^4)*8);
  }

  #pragma unroll
  for (int t = 0; t < NTK; ++t){
    const int par = t & 1, nxt = par ^ 1;
    const unsigned short* Ab  = AsB + (t % 3)*LDS_A_BUF;
    const unsigned short* Abn = AsB + ((t+1) % 3)*LDS_A_BUF;
    const unsigned short* Bbn = BsB + ((t+1) % 3)*LDS_B_BUF;
    unsigned short* Ast = AsB + ((t+2) % 3)*LDS_A_BUF;
    unsigned short* Bst = BsB + ((t+2) % 3)*LDS_B_BUF;
    const int kst = (t + 2) * BK;

    // ---------------- phase A ----------------
    LGKM0();                                  // last phase's reads done (aged ~1 phase)
    #pragma unroll
    for (int mi = 0; mi < 2; mi++){
      const unsigned short* pr = Ab + (wm + (2+mi)*16 + l15)*BK;
      a23[mi][0] = *(const short8*)(pr + s0*8);
      a23[mi][1] = *(const short8*)(pr + (s0^4)*8);
    }
    if (t + 2 < NTK) stage_part(A, Bm, m0, n0, kst, Ast, Bst, tid, 0);
    SCHEDB();                                 // pin reads/stage before MFMA burst
    __builtin_amdgcn_s_setprio(1);
    #pragma unroll
    for (int mi = 0; mi < 2; mi++)
      #pragma unroll
      for (int ni = 0; ni < 4; ni++){
        acc[mi][ni] = __builtin_amdgcn_mfma_f32_16x16x32_bf16(a01[mi][0], b[par][ni][0], acc[mi][ni], 0, 0, 0);
        acc[mi][ni] = __builtin_amdgcn_mfma_f32_16x16x32_bf16(a01[mi][1], b[par][ni][1], acc[mi][ni], 0, 0, 0);
      }
    __builtin_amdgcn_s_setprio(0);
    if (t + 2 < NTK)      { VMCNT3(); }       // t+1's 6 drained; t+2p0's 3 in flight
    else if (t + 1 < NTK) { VMCNT0(); }       // tail: drain last tile fully
    BARRIER();                                // publishes buf t+1

    // ---------------- phase B ----------------
    LGKM0();                                  // a23 reads done
    if (t + 1 < NTK){
      #pragma unroll
      for (int mi = 0; mi < 2; mi++){
        const unsigned short* pr = Abn + (wm + mi*16 + l15)*BK;
        a01[mi][0] = *(const short8*)(pr + s0*8);
        a01[mi][1] = *(const short8*)(pr + (s0^4)*8);
      }
      #pragma unroll
      for (int ni = 0; ni < 4; ni++){
        const unsigned short* pr = Bbn + (wn + ni*16 + l15)*BK;
        b[nxt][ni][0] = *(const short8*)(pr + s0*8);
        b[nxt][ni][1] = *(const short8*)(pr + (s0^4)*8);
      }
    }
    if (t + 2 < NTK) stage_part(A, Bm, m0, n0, kst, Ast, Bst, tid, 1);
    SCHEDB();
    __builtin_amdgcn_s_setprio(1);
    #pragma unroll
    for (int mi = 0; mi < 2; mi++)
      #pragma unroll
      for (int ni = 0; ni < 4; ni++){
        acc[2+mi][ni] = __builtin_amdgcn_mfma_f32_16x16x32_bf16(a23[mi][0], b[par][ni][0], acc[2+mi][ni], 0, 0, 0);
        acc[2+mi][ni] = __builtin_amdgcn_mfma_f32_16x16x32_bf16(a23[mi][1], b[par][ni][1], acc[2+mi][ni], 0, 0, 0);
      }
    __builtin_amdgcn_s_setprio(0);
    if (t + 1 < NTK) BARRIER();
  }
}

// ---------------- QKV GEMM with fused RoPE (Q,K) and transposed-V epilogue ----------------
__global__ __launch_bounds__(512, 2) void gemm_qkv(
    const unsigned short* __restrict__ Xb,
    const unsigned short* __restrict__ Wq,
    const unsigned short* __restrict__ Wk,
    const unsigned short* __restrict__ Wv,
    const int* __restrict__ pos,
    unsigned short* __restrict__ Qo,
    unsigned short* __restrict__ Ko,
    unsigned short* __restrict__ VTo)
{
  __shared__ __align__(16) unsigned short Ls[3*LDS_A_BUF + 3*LDS_B_BUF];  // 144 KiB
  int m0 = blockIdx.x * BM;
  int n0 = blockIdx.y * BN;
  int z  = blockIdx.z;
  const unsigned short* Bmat = (z == 0) ? Wq : ((z == 1) ? Wk : Wv);
  unsigned short* Out = (z == 0) ? Qo : ((z == 1) ? Ko : VTo);

  int tid = threadIdx.x;
  floatx4 acc[4][4] = {};
  gemm_core(Xb, Bmat, m0, n0, Ls, tid, acc);

  int wave = tid >> 6, lane = tid & 63;
  int l15 = lane & 15, quad = lane >> 4;
  int wm = (wave >> 1) * 64, wn = (wave & 1) * 64;

  if (z == 2){
    #pragma unroll
    for (int mi = 0; mi < 4; mi++){
      int row0 = m0 + wm + mi * 16 + quad * 4;
      int bb2 = row0 >> 11, sQ = row0 & (S_LEN - 1);
      #pragma unroll
      for (int ni = 0; ni < 4; ni++){
        int col = n0 + wn + ni * 16 + l15;
        int h = col >> 6, d = col & 63;
        ushort4 u;
        u.x = f2bf(acc[mi][ni][0]); u.y = f2bf(acc[mi][ni][1]);
        u.z = f2bf(acc[mi][ni][2]); u.w = f2bf(acc[mi][ni][3]);
        *(ushort4*)&Out[(((size_t)bb2 * NH + h) * DK + d) * S_LEN + sQ] = u;
      }
    }
  } else {
    // RoPE via hardware v_sin/v_cos (revolutions): no libm calls -> no spills.
    const float SC = (z == 0) ? 0.180336879f : 1.0f;   // 0.125 * log2(e) for Q
    #pragma unroll
    for (int mi = 0; mi < 4; mi++){
      #pragma unroll
      for (int ni = 0; ni < 4; ni++){
        int col = n0 + wn + ni * 16 + l15;
        int h = col >> 6, d = col & 63;
        int fi = d >> 1, odd = d & 1;
        float invfrev = fast_exp2(-(float)fi * (13.2877123795494f / 32.0f)) * 0.15915494309f;
        #pragma unroll
        for (int r = 0; r < 4; r++){
          int row = m0 + wm + mi * 16 + quad * 4 + r;
          int bb2 = row >> 11, s = row & (S_LEN - 1);
          float p = (float)pos[s];
          float rev = p * invfrev;
          rev = rev - floorf(rev);
          float c  = __builtin_amdgcn_cosf(rev);
          float sn = __builtin_amdgcn_sinf(rev);
          float val = acc[mi][ni][r];
          float other = __shfl_xor(val, 1);
          float outv = odd ? (other * sn + val * c) : (val * c - other * sn);
          Out[(((size_t)bb2 * NH + h) * S_LEN + s) * DK + d] = f2bf(outv * SC);
        }
      }
    }
  }
}

// ---------------- Output projection GEMM: fp32 out ----------------
__global__ __launch_bounds__(512, 2) void gemm_out(
    const unsigned short* __restrict__ Ab,
    const unsigned short* __restrict__ Wo,
    float* __restrict__ Out)
{
  __shared__ __align__(16) unsigned short Ls[3*LDS_A_BUF + 3*LDS_B_BUF];
  int m0 = blockIdx.x * BM;
  int n0 = blockIdx.y * BN;

  int tid = threadIdx.x;
  floatx4 acc[4][4] = {};
  gemm_core(Ab, Wo, m0, n0, Ls, tid, acc);

  int wave = tid >> 6, lane = tid & 63;
  int l15 = lane & 15, quad = lane >> 4;
  int wm = (wave >> 1) * 64, wn = (wave & 1) * 64;

  #pragma unroll
  for (int mi = 0; mi < 4; mi++){
    #pragma unroll
    for (int ni = 0; ni < 4; ni++){
      #pragma unroll
      for (int r = 0; r < 4; r++){
        int row = m0 + wm + mi * 16 + quad * 4 + r;
        int col = n0 + wn + ni * 16 + l15;
        Out[(size_t)row * DM + col] = acc[mi][ni][r];
      }
    }
  }
}

// ---------------- Flash attention (causal), swapped-operand, in-register P ----
// Q pre-scaled by 0.125*log2(e) -> p = exp2(score); masked -> -inf -> 0.
// QK^T computed SWAPPED: mfma(A=K, B=Q) so D col (lane&15) = q, D row
// (quad*4+reg) = kv.  Each lane owns one q row => softmax row-sum is in-lane
// (16 kv values) + 2 cross-quad shuffles at the end.  The PV B-operand
// P[q=l15][kv=quad*8+e] is built from the QK output by a derived 4-quad
// exchange: dest(quad qh, word j, half h2) <- src lane (l15 + 16*(2*(qh&1)+
// (j>>1))), register u[2*h2+(qh>>1)][j&1], where u[ni][w]=pk(p[ni][2w],
// p[ni][2w+1]).  This removes the Ps LDS round-trip entirely => K/V double-
// buffered in the same 36.9KB (4 blocks/CU) and ONE barrier per tile.
// Heavy q-blocks dispatch FIRST (y reversed) so the drain tail is light.
__global__ __launch_bounds__(256, 4) void attn_kernel(
    const unsigned short* __restrict__ Qg,
    const unsigned short* __restrict__ Kg,
    const unsigned short* __restrict__ VTg,
    unsigned short* __restrict__ Ao)
{
  __shared__ __align__(16) unsigned short Ks[2][KVT * KPAD];   // [buf][kv][dk] natural rows
  __shared__ __align__(16) unsigned short Vs[2][DK * KPAD];    // [buf][d][kv] natural

  int bh = blockIdx.x;
  int q0 = ((int)gridDim.y - 1 - (int)blockIdx.y) * QB;   // heavy-first
  int tid = threadIdx.x, wave = tid >> 6, lane = tid & 63;
  int l15 = lane & 15, quad = lane >> 4;
  int qw = q0 + wave * 32;

  const unsigned short* Qb = Qg + (size_t)bh * S_LEN * DK;
  const unsigned short* Kb = Kg + (size_t)bh * S_LEN * DK;
  const unsigned short* Vb = VTg + (size_t)bh * DK * S_LEN;

  // Q fragments (B-operand): row = l15 = q, k-chunk = quad*8 (+32)
  short8 aq[2][2];
  #pragma unroll
  for (int mi = 0; mi < 2; mi++){
    aq[mi][0] = *(const short8*)&Qb[(qw + mi * 16 + l15) * DK + quad * 8];
    aq[mi][1] = *(const short8*)&Qb[(qw + mi * 16 + l15) * DK + 32 + quad * 8];
  }

  floatx4 o2[2][4] = {};                 // [mi][dt]: row=d (quad*4+r), col=q (l15)
  float lsum[2] = {0.f, 0.f};

  int srow = tid >> 2;                   // kv row (K) / d row (V)
  int scol = (tid & 3) * 16;
  const unsigned short* Krow = Kb + (size_t)srow * DK + scol;
  const unsigned short* Vrow = Vb + (size_t)srow * S_LEN + scol;

  int nt = q0 / KVT + 2;

  // shuffle source lanes (see header comment)
  int sl0 = l15 + ((lane & 16) << 1);    // l15 + 32*(quad&1)  -> words j=0,1
  int sl1 = sl0 + 16;                    //                      -> words j=2,3
  bool niHi = (lane & 32) != 0;          // quad>=2 selects odd ni

  // prefetch tile 0 into registers
  short8 kr0 = *(const short8*)(Krow);
  short8 kr1 = *(const short8*)(Krow + 8);
  short8 vr0 = *(const short8*)(Vrow);
  short8 vr1 = *(const short8*)(Vrow + 8);

  for (int kt = 0; kt < nt; kt++){
    int kv0 = kt * KVT;
    int p = kt & 1;
    // write K/V(kt) into buf p (prior readers of buf p finished before barrier kt-1)
    *(short8*)&Ks[p][srow * KPAD + scol]     = kr0;
    *(short8*)&Ks[p][srow * KPAD + scol + 8] = kr1;
    *(short8*)&Vs[p][srow * KPAD + scol]     = vr0;
    *(short8*)&Vs[p][srow * KPAD + scol + 8] = vr1;
    if (kt + 1 < nt){                   // prefetch next tile (hides under compute)
      int kvn = kv0 + KVT;
      kr0 = *(const short8*)(Krow + (size_t)kvn * DK);
      kr1 = *(const short8*)(Krow + (size_t)kvn * DK + 8);
      vr0 = *(const short8*)(Vrow + kvn);
      vr1 = *(const short8*)(Vrow + kvn + 8);
    }
    LGKM0();                            // own ds_writes complete
    BARRIER();                          // tile ready; single barrier per tile

    if (kv0 <= qw + 31){
      // ---- QK^T swapped: A=K rows (natural), B=Q ----
      floatx4 s2[2][4] = {};
      #pragma unroll
      for (int ni = 0; ni < 4; ni++){
        short8 bk0 = *(const short8*)&Ks[p][(ni * 16 + l15) * KPAD + quad * 8];
        short8 bk1 = *(const short8*)&Ks[p][(ni * 16 + l15) * KPAD + 32 + quad * 8];
        #pragma unroll
        for (int mi = 0; mi < 2; mi++){
          s2[mi][ni] = __builtin_amdgcn_mfma_f32_16x16x32_bf16(bk0, aq[mi][0], s2[mi][ni], 0, 0, 0);
          s2[mi][ni] = __builtin_amdgcn_mfma_f32_16x16x32_bf16(bk1, aq[mi][1], s2[mi][ni], 0, 0, 0);
        }
      }
      bool full = (kv0 + 63 <= qw);
      short8 pw[2][2];                  // [mi][h2] PV B-operand fragments
      #pragma unroll
      for (int mi = 0; mi < 2; mi++){
        int qg = qw + mi * 16 + l15;    // this lane's q row
        unsigned int u[4][2];
        float ls = 0.f;
        #pragma unroll
        for (int ni = 0; ni < 4; ni++){
          int kvb = kv0 + ni * 16 + quad * 4;
          float v0 = s2[mi][ni][0], v1 = s2[mi][ni][1], v2 = s2[mi][ni][2], v3 = s2[mi][ni][3];
          if (!full){
            v0 = (kvb     > qg) ? -INFINITY : v0;
            v1 = (kvb + 1 > qg) ? -INFINITY : v1;
            v2 = (kvb + 2 > qg) ? -INFINITY : v2;
            v3 = (kvb + 3 > qg) ? -INFINITY : v3;
          }
          float p0 = fast_exp2(v0);
          float p1 = fast_exp2(v1);
          float p2 = fast_exp2(v2);
          float p3 = fast_exp2(v3);
          ls += (p0 + p1) + (p2 + p3);
          u[ni][0] = pk_bf_trunc(p0, p1);
          u[ni][1] = pk_bf_trunc(p2, p3);
        }
        lsum[mi] += ls;
        // ---- 4-quad exchange: build P[q=l15][kv=quad*8+e] ----
        #pragma unroll
        for (int h2 = 0; h2 < 2; h2++){
          unsigned int we0 = (unsigned int)__shfl((int)u[2*h2][0],   sl0);
          unsigned int wo0 = (unsigned int)__shfl((int)u[2*h2+1][0], sl0);
          unsigned int we1 = (unsigned int)__shfl((int)u[2*h2][1],   sl0);
          unsigned int wo1 = (unsigned int)__shfl((int)u[2*h2+1][1], sl0);
          unsigned int we2 = (unsigned int)__shfl((int)u[2*h2][0],   sl1);
          unsigned int wo2 = (unsigned int)__shfl((int)u[2*h2+1][0], sl1);
          unsigned int we3 = (unsigned int)__shfl((int)u[2*h2][1],   sl1);
          unsigned int wo3 = (unsigned int)__shfl((int)u[2*h2+1][1], sl1);
          union { unsigned int w[4]; short8 v; } pb;
          pb.w[0] = niHi ? wo0 : we0;
          pb.w[1] = niHi ? wo1 : we1;
          pb.w[2] = niHi ? wo2 : we2;
          pb.w[3] = niHi ? wo3 : we3;
          pw[mi][h2] = pb.v;
        }
      }
      // ---- PV: A = V^T rows (d), B = P; D row=d, col=q ----
      #pragma unroll
      for (int dt = 0; dt < 4; dt++){
        short8 bv0 = *(const short8*)&Vs[p][(dt * 16 + l15) * KPAD + quad * 8];
        short8 bv1 = *(const short8*)&Vs[p][(dt * 16 + l15) * KPAD + 32 + quad * 8];
        #pragma unroll
        for (int mi = 0; mi < 2; mi++){
          o2[mi][dt] = __builtin_amdgcn_mfma_f32_16x16x32_bf16(bv0, pw[mi][0], o2[mi][dt], 0, 0, 0);
          o2[mi][dt] = __builtin_amdgcn_mfma_f32_16x16x32_bf16(bv1, pw[mi][1], o2[mi][dt], 0, 0, 0);
        }
      }
    }
  }

  // finalize row sums: this lane covered kv quads {quad}; combine 4 quads
  float linv[2];
  #pragma unroll
  for (int mi = 0; mi < 2; mi++){
    float rs = lsum[mi];
    rs += __shfl_xor(rs, 16);
    rs += __shfl_xor(rs, 32);
    linv[mi] = 1.0f / rs;
  }

  int bq = bh >> 4, hq = bh & 15;
  #pragma unroll
  for (int mi = 0; mi < 2; mi++){
    int s = qw + mi * 16 + l15;
    #pragma unroll
    for (int dt = 0; dt < 4; dt++){
      ushort4 uo;
      uo.x = f2bf(o2[mi][dt][0] * linv[mi]);
      uo.y = f2bf(o2[mi][dt][1] * linv[mi]);
      uo.z = f2bf(o2[mi][dt][2] * linv[mi]);
      uo.w = f2bf(o2[mi][dt][3] * linv[mi]);
      *(ushort4*)&Ao[(((size_t)bq * S_LEN + s) * NH + hq) * DK + dt * 16 + quad * 4] = uo;
    }
  }
}

extern "C" void kernel_launch(void* const* d_in, const int* in_sizes, int n_in,
                              void* d_out, int out_size, void* d_ws, size_t ws_size,
                              hipStream_t stream) {
  (void)in_sizes; (void)n_in; (void)out_size; (void)ws_size;
  const float* Wq = (const float*)d_in[0];
  const float* Wk = (const float*)d_in[1];
  const float* Wv = (const float*)d_in[2];
  const float* Wo = (const float*)d_in[3];
  const float* X  = (const float*)d_in[4];
  const int* pos  = (const int*)d_in[5];
  float* out = (float*)d_out;

  char* ws = (char*)d_ws;
  const size_t MB = 1024 * 1024;
  unsigned short* Xb  = (unsigned short*)(ws);             // 16 MB
  unsigned short* Wqb = (unsigned short*)(ws + 16 * MB);   // 2 MB
  unsigned short* Wkb = (unsigned short*)(ws + 18 * MB);
  unsigned short* Wvb = (unsigned short*)(ws + 20 * MB);
  unsigned short* Wob = (unsigned short*)(ws + 22 * MB);
  unsigned short* Qb  = (unsigned short*)(ws + 24 * MB);   // 16 MB
  unsigned short* Kb  = (unsigned short*)(ws + 40 * MB);
  unsigned short* Vb  = (unsigned short*)(ws + 56 * MB);   // transposed [bh][dk][S]
  unsigned short* Ab  = (unsigned short*)(ws + 72 * MB);

  cast_kernel<<<8192, 256, 0, stream>>>(X,  Xb,  M_TOT * DM);
  cast4_kernel<<<dim3(1024, 4), 256, 0, stream>>>(Wq, Wk, Wv, Wo, Wqb, Wkb, Wvb, Wob);

  gemm_qkv<<<dim3(M_TOT/BM, DM/BN, 3), 512, 0, stream>>>(Xb, Wqb, Wkb, Wvb, pos, Qb, Kb, Vb);
  attn_kernel<<<dim3(64, S_LEN / QB), 256, 0, stream>>>(Qb, Kb, Vb, Ab);
  gemm_out<<<dim3(M_TOT/BM, DM/BN), 512, 0, stream>>>(Ab, Wob, out);
}

// Round 5
// 243.553 us; speedup vs baseline: 1.1106x; 1.1106x over previous
//
#include <hip/hip_runtime.h>
#include <stdint.h>
#include <math.h>

#define NH 16
#define DK 64
#define S_LEN 2048
#define BB 4
#define DM 1024
#define M_TOT (BB*S_LEN) // 8192
#define KVT 64
#define KPAD 72
#define QB 128

// ---- GEMM geometry: 256x128 tile, BK=64, 8 waves (4M x 2N), triple-buffered LDS ----
#define BM 256
#define BN 128
#define BK 64
#define NTK (DM/BK)            // 16 K-tiles
#define LDS_A_BUF (BM*BK)      // 16384 ushort per buffer
#define LDS_B_BUF (BN*BK)      // 8192 ushort per buffer

typedef __attribute__((ext_vector_type(8))) short short8;
typedef __attribute__((ext_vector_type(4))) float floatx4;

typedef const __attribute__((address_space(1))) void gas_t;
typedef __attribute__((address_space(3))) void las_t;

__device__ __forceinline__ void glds16(const void* g, void* l){
  __builtin_amdgcn_global_load_lds((gas_t*)g, (las_t*)l, 16, 0, 0);
}

// Sync primitives: inline-asm with "memory" clobber = compiler fence too.
#define VMCNT3() asm volatile("s_waitcnt vmcnt(3)" ::: "memory")
#define VMCNT6() asm volatile("s_waitcnt vmcnt(6)" ::: "memory")
#define VMCNT0() asm volatile("s_waitcnt vmcnt(0)" ::: "memory")
#define LGKM0()  do{ asm volatile("s_waitcnt lgkmcnt(0)" ::: "memory"); __builtin_amdgcn_sched_barrier(0); }while(0)
#define BARRIER() asm volatile("s_barrier" ::: "memory")
#define SCHEDB() __builtin_amdgcn_sched_barrier(0)

__device__ __forceinline__ unsigned short f2bf(float f){
  unsigned int u = __float_as_uint(f);
  u += 0x7fffu + ((u >> 16) & 1u);
  return (unsigned short)(u >> 16);
}
// pack hi16(b):hi16(a) in one v_perm_b32 (truncation-rounded bf16 pair)
__device__ __forceinline__ unsigned int pk_bf_trunc(float a, float b){
  return __builtin_amdgcn_perm(__float_as_uint(b), __float_as_uint(a), 0x07060302u);
}
__device__ __forceinline__ float fast_exp2(float x){
  return __builtin_amdgcn_exp2f(x);
}

// ---------------- cast fp32 -> bf16, all five tensors in ONE launch ----------------
// blocks 0..8191: X (8192*1024 elems); 8192+1024*w: weight w (1024*1024 each).
__global__ void cast_all(const float* __restrict__ X,
                         const float* __restrict__ Wq, const float* __restrict__ Wk,
                         const float* __restrict__ Wv, const float* __restrict__ Wo,
                         unsigned short* __restrict__ Xb,
                         unsigned short* __restrict__ Wqb, unsigned short* __restrict__ Wkb,
                         unsigned short* __restrict__ Wvb, unsigned short* __restrict__ Wob)
{
  int b = blockIdx.x;
  const float* s;
  unsigned short* o;
  int base;
  if (b < 8192){ s = X; o = Xb; base = b; }
  else {
    int w = (b - 8192) >> 10;
    base = (b - 8192) & 1023;
    s = (w == 0) ? Wq : (w == 1) ? Wk : (w == 2) ? Wv : Wo;
    o = (w == 0) ? Wqb : (w == 1) ? Wkb : (w == 2) ? Wvb : Wob;
  }
  int i = base * 1024 + threadIdx.x * 4;
  float4 v = *(const float4*)(s + i);
  ushort4 u;
  u.x = f2bf(v.x); u.y = f2bf(v.y); u.z = f2bf(v.z); u.w = f2bf(v.w);
  *(ushort4*)(o + i) = u;
}

// Stage half of one K-tile (3 x glds16: 2 A-chunks + 1 B-chunk per thread).
// LDS dest is lane-linear (global_load_lds requirement); bank-conflict-free reads
// come from XOR-swizzling the SOURCE address: phys 16B-slot p of row r holds
// logical slot p^(r&7).  (Verified: SQ_LDS_BANK_CONFLICT == 0.)
__device__ __forceinline__ void stage_part(const unsigned short* __restrict__ A,
                                           const unsigned short* __restrict__ Bm,
                                           int m0, int n0, int k0,
                                           unsigned short* As, unsigned short* Bs,
                                           int tid, int part)
{
  if (part == 0){
    #pragma unroll
    for (int j = 0; j < 2; j++){
      int c = j*512 + tid;                 // 16B chunk index; row has 8 chunks (128B)
      int r = c >> 3;
      int sl = (c & 7) ^ (r & 7);
      glds16(&A[(size_t)(m0 + r)*DM + k0 + sl*8], (char*)As + (size_t)c*16);
    }
    int c = tid;
    int r = c >> 3;
    int sl = (c & 7) ^ (r & 7);
    glds16(&Bm[(size_t)(n0 + r)*DM + k0 + sl*8], (char*)Bs + (size_t)c*16);
  } else {
    #pragma unroll
    for (int j = 2; j < 4; j++){
      int c = j*512 + tid;
      int r = c >> 3;
      int sl = (c & 7) ^ (r & 7);
      glds16(&A[(size_t)(m0 + r)*DM + k0 + sl*8], (char*)As + (size_t)c*16);
    }
    int c = 512 + tid;
    int r = c >> 3;
    int sl = (c & 7) ^ (r & 7);
    glds16(&Bm[(size_t)(n0 + r)*DM + k0 + sl*8], (char*)Bs + (size_t)c*16);
  }
}

// Triple-buffered, counted-vmcnt, phase-interleaved K-loop with REGISTER
// SOFTWARE PIPELINING: each phase's MFMA consumes fragments ds_read a full
// phase earlier.  MFMA burst is emitted k-split (all 8 cells at k0, then all
// at k1) so no two back-to-back MFMAs share an accumulator (dep distance 8);
// per-cell accumulation order (k0 then k1) unchanged -> bit-identical.
__device__ __forceinline__ void gemm_core(const unsigned short* __restrict__ A,
                                          const unsigned short* __restrict__ Bm,
                                          int m0, int n0, unsigned short* Ls,
                                          int tid, floatx4 (&acc)[4][4])
{
  unsigned short* AsB = Ls;                   // 3 x LDS_A_BUF
  unsigned short* BsB = Ls + 3*LDS_A_BUF;     // 3 x LDS_B_BUF
  int wave = tid >> 6, lane = tid & 63;
  int l15 = lane & 15, quad = lane >> 4;
  int wm = (wave >> 1) * 64, wn = (wave & 1) * 64;
  int s0 = quad ^ (l15 & 7);                  // swizzled slot for kk=0; kk=1 is s0^4

  short8 a01[2][2], a23[2][2], b[2][4][2];    // b parity-indexed (live both phases)

  // ---- prologue: stage tiles 0,1; pre-read fragsA(0)+b(0) ----
  stage_part(A, Bm, m0, n0, 0,  AsB,             BsB,             tid, 0);
  stage_part(A, Bm, m0, n0, 0,  AsB,             BsB,             tid, 1);
  stage_part(A, Bm, m0, n0, BK, AsB + LDS_A_BUF, BsB + LDS_B_BUF, tid, 0);
  stage_part(A, Bm, m0, n0, BK, AsB + LDS_A_BUF, BsB + LDS_B_BUF, tid, 1);
  VMCNT6();                                   // tile0 landed; tile1 in flight
  BARRIER();
  #pragma unroll
  for (int mi = 0; mi < 2; mi++){
    const unsigned short* pr = AsB + (wm + mi*16 + l15)*BK;
    a01[mi][0] = *(const short8*)(pr + s0*8);
    a01[mi][1] = *(const short8*)(pr + (s0^4)*8);
  }
  #pragma unroll
  for (int ni = 0; ni < 4; ni++){
    const unsigned short* pr = BsB + (wn + ni*16 + l15)*BK;
    b[0][ni][0] = *(const short8*)(pr + s0*8);
    b[0][ni][1] = *(const short8*)(pr + (s0^4)*8);
  }

  #pragma unroll
  for (int t = 0; t < NTK; ++t){
    const int par = t & 1, nxt = par ^ 1;
    const unsigned short* Ab  = AsB + (t % 3)*LDS_A_BUF;
    const unsigned short* Abn = AsB + ((t+1) % 3)*LDS_A_BUF;
    const unsigned short* Bbn = BsB + ((t+1) % 3)*LDS_B_BUF;
    unsigned short* Ast = AsB + ((t+2) % 3)*LDS_A_BUF;
    unsigned short* Bst = BsB + ((t+2) % 3)*LDS_B_BUF;
    const int kst = (t + 2) * BK;

    // ---------------- phase A ----------------
    LGKM0();                                  // last phase's reads done (aged ~1 phase)
    #pragma unroll
    for (int mi = 0; mi < 2; mi++){
      const unsigned short* pr = Ab + (wm + (2+mi)*16 + l15)*BK;
      a23[mi][0] = *(const short8*)(pr + s0*8);
      a23[mi][1] = *(const short8*)(pr + (s0^4)*8);
    }
    if (t + 2 < NTK) stage_part(A, Bm, m0, n0, kst, Ast, Bst, tid, 0);
    SCHEDB();                                 // pin reads/stage before MFMA burst
    __builtin_amdgcn_s_setprio(1);
    #pragma unroll
    for (int kk = 0; kk < 2; kk++)
      #pragma unroll
      for (int mi = 0; mi < 2; mi++)
        #pragma unroll
        for (int ni = 0; ni < 4; ni++)
          acc[mi][ni] = __builtin_amdgcn_mfma_f32_16x16x32_bf16(a01[mi][kk], b[par][ni][kk], acc[mi][ni], 0, 0, 0);
    __builtin_amdgcn_s_setprio(0);
    if (t + 2 < NTK)      { VMCNT3(); }       // t+1's 6 drained; t+2p0's 3 in flight
    else if (t + 1 < NTK) { VMCNT0(); }       // tail: drain last tile fully
    BARRIER();                                // publishes buf t+1

    // ---------------- phase B ----------------
    LGKM0();                                  // a23 reads done
    if (t + 1 < NTK){
      #pragma unroll
      for (int mi = 0; mi < 2; mi++){
        const unsigned short* pr = Abn + (wm + mi*16 + l15)*BK;
        a01[mi][0] = *(const short8*)(pr + s0*8);
        a01[mi][1] = *(const short8*)(pr + (s0^4)*8);
      }
      #pragma unroll
      for (int ni = 0; ni < 4; ni++){
        const unsigned short* pr = Bbn + (wn + ni*16 + l15)*BK;
        b[nxt][ni][0] = *(const short8*)(pr + s0*8);
        b[nxt][ni][1] = *(const short8*)(pr + (s0^4)*8);
      }
    }
    if (t + 2 < NTK) stage_part(A, Bm, m0, n0, kst, Ast, Bst, tid, 1);
    SCHEDB();
    __builtin_amdgcn_s_setprio(1);
    #pragma unroll
    for (int kk = 0; kk < 2; kk++)
      #pragma unroll
      for (int mi = 0; mi < 2; mi++)
        #pragma unroll
        for (int ni = 0; ni < 4; ni++)
          acc[2+mi][ni] = __builtin_amdgcn_mfma_f32_16x16x32_bf16(a23[mi][kk], b[par][ni][kk], acc[2+mi][ni], 0, 0, 0);
    __builtin_amdgcn_s_setprio(0);
    if (t + 1 < NTK) BARRIER();
  }
}

// ---------------- QKV GEMM with fused RoPE (Q,K) and transposed-V epilogue ----------------
__global__ __launch_bounds__(512, 2) void gemm_qkv(
    const unsigned short* __restrict__ Xb,
    const unsigned short* __restrict__ Wq,
    const unsigned short* __restrict__ Wk,
    const unsigned short* __restrict__ Wv,
    const int* __restrict__ pos,
    unsigned short* __restrict__ Qo,
    unsigned short* __restrict__ Ko,
    unsigned short* __restrict__ VTo)
{
  __shared__ __align__(16) unsigned short Ls[3*LDS_A_BUF + 3*LDS_B_BUF];  // 144 KiB
  int m0 = blockIdx.x * BM;
  int n0 = blockIdx.y * BN;
  int z  = blockIdx.z;
  const unsigned short* Bmat = (z == 0) ? Wq : ((z == 1) ? Wk : Wv);
  unsigned short* Out = (z == 0) ? Qo : ((z == 1) ? Ko : VTo);

  int tid = threadIdx.x;
  floatx4 acc[4][4] = {};
  gemm_core(Xb, Bmat, m0, n0, Ls, tid, acc);

  int wave = tid >> 6, lane = tid & 63;
  int l15 = lane & 15, quad = lane >> 4;
  int wm = (wave >> 1) * 64, wn = (wave & 1) * 64;

  if (z == 2){
    #pragma unroll
    for (int mi = 0; mi < 4; mi++){
      int row0 = m0 + wm + mi * 16 + quad * 4;
      int bb2 = row0 >> 11, sQ = row0 & (S_LEN - 1);
      #pragma unroll
      for (int ni = 0; ni < 4; ni++){
        int col = n0 + wn + ni * 16 + l15;
        int h = col >> 6, d = col & 63;
        ushort4 u;
        u.x = f2bf(acc[mi][ni][0]); u.y = f2bf(acc[mi][ni][1]);
        u.z = f2bf(acc[mi][ni][2]); u.w = f2bf(acc[mi][ni][3]);
        *(ushort4*)&Out[(((size_t)bb2 * NH + h) * DK + d) * S_LEN + sQ] = u;
      }
    }
  } else {
    // RoPE via hardware v_sin/v_cos (revolutions): no libm calls -> no spills.
    const float SC = (z == 0) ? 0.180336879f : 1.0f;   // 0.125 * log2(e) for Q
    #pragma unroll
    for (int mi = 0; mi < 4; mi++){
      #pragma unroll
      for (int ni = 0; ni < 4; ni++){
        int col = n0 + wn + ni * 16 + l15;
        int h = col >> 6, d = col & 63;
        int fi = d >> 1, odd = d & 1;
        float invfrev = fast_exp2(-(float)fi * (13.2877123795494f / 32.0f)) * 0.15915494309f;
        #pragma unroll
        for (int r = 0; r < 4; r++){
          int row = m0 + wm + mi * 16 + quad * 4 + r;
          int bb2 = row >> 11, s = row & (S_LEN - 1);
          float p = (float)pos[s];
          float rev = p * invfrev;
          rev = rev - floorf(rev);
          float c  = __builtin_amdgcn_cosf(rev);
          float sn = __builtin_amdgcn_sinf(rev);
          float val = acc[mi][ni][r];
          float other = __shfl_xor(val, 1);
          float outv = odd ? (other * sn + val * c) : (val * c - other * sn);
          Out[(((size_t)bb2 * NH + h) * S_LEN + s) * DK + d] = f2bf(outv * SC);
        }
      }
    }
  }
}

// ---------------- Output projection GEMM: fp32 out ----------------
__global__ __launch_bounds__(512, 2) void gemm_out(
    const unsigned short* __restrict__ Ab,
    const unsigned short* __restrict__ Wo,
    float* __restrict__ Out)
{
  __shared__ __align__(16) unsigned short Ls[3*LDS_A_BUF + 3*LDS_B_BUF];
  int m0 = blockIdx.x * BM;
  int n0 = blockIdx.y * BN;

  int tid = threadIdx.x;
  floatx4 acc[4][4] = {};
  gemm_core(Ab, Wo, m0, n0, Ls, tid, acc);

  int wave = tid >> 6, lane = tid & 63;
  int l15 = lane & 15, quad = lane >> 4;
  int wm = (wave >> 1) * 64, wn = (wave & 1) * 64;

  #pragma unroll
  for (int mi = 0; mi < 4; mi++){
    #pragma unroll
    for (int ni = 0; ni < 4; ni++){
      #pragma unroll
      for (int r = 0; r < 4; r++){
        int row = m0 + wm + mi * 16 + quad * 4 + r;
        int col = n0 + wn + ni * 16 + l15;
        Out[(size_t)row * DM + col] = acc[mi][ni][r];
      }
    }
  }
}

// ---------------- Flash attention (causal), no-max softmax, pipelined ----------------
// (round-3 version, reverted: shuffle-exchange variant regressed 64.8->93.7us)
// Q pre-scaled by 0.125*log2(e) -> p = exp2(score); masked -> -inf -> 0.
// K rows permuted in LDS: pos(kv) = (kv&3)*16 + (kv>>2) so MFMA col ni*16+l15
// = actual kv 4*l15+ni -> each lane's 4 p-values are contiguous -> one b64
// write per row (packed with v_perm truncation).
// Heavy q-blocks dispatch FIRST (y reversed) so the drain tail is light blocks.
__global__ __launch_bounds__(256) void attn_kernel(
    const unsigned short* __restrict__ Qg,
    const unsigned short* __restrict__ Kg,
    const unsigned short* __restrict__ VTg,
    unsigned short* __restrict__ Ao)
{
  __shared__ __align__(16) unsigned short Ks[KVT * KPAD];   // [pos][dk] permuted rows
  __shared__ __align__(16) unsigned short Vs[DK * KPAD];    // [d][kv] natural
  __shared__ __align__(16) unsigned short Ps[4][32 * KPAD]; // per-wave P, natural kv cols

  int bh = blockIdx.x;
  int q0 = ((int)gridDim.y - 1 - (int)blockIdx.y) * QB;   // heavy-first
  int tid = threadIdx.x, wave = tid >> 6, lane = tid & 63;
  int l15 = lane & 15, quad = lane >> 4;
  int qw = q0 + wave * 32;

  const unsigned short* Qb = Qg + (size_t)bh * S_LEN * DK;
  const unsigned short* Kb = Kg + (size_t)bh * S_LEN * DK;
  const unsigned short* Vb = VTg + (size_t)bh * DK * S_LEN;

  short8 aq[2][2];
  #pragma unroll
  for (int mi = 0; mi < 2; mi++){
    aq[mi][0] = *(const short8*)&Qb[(qw + mi * 16 + l15) * DK + quad * 8];
    aq[mi][1] = *(const short8*)&Qb[(qw + mi * 16 + l15) * DK + 32 + quad * 8];
  }

  floatx4 o[2][4] = {};
  float lsum[2][4] = {{0.f,0.f,0.f,0.f},{0.f,0.f,0.f,0.f}};

  int srow = tid >> 2;                 // kv row (K) / d row (V)
  int scol = (tid & 3) * 16;
  int kpos = (srow & 3) * 16 + (srow >> 2);   // permuted K row position
  const unsigned short* Krow = Kb + (size_t)srow * DK + scol;
  const unsigned short* Vrow = Vb + (size_t)srow * S_LEN + scol;
  unsigned short* KsW = &Ks[kpos * KPAD + scol];
  unsigned short* VsW = &Vs[srow * KPAD + scol];

  int nt = q0 / KVT + 2;

  // prefetch tile 0 into registers
  short8 kr0 = *(const short8*)(Krow);
  short8 kr1 = *(const short8*)(Krow + 8);
  short8 vr0 = *(const short8*)(Vrow);
  short8 vr1 = *(const short8*)(Vrow + 8);

  for (int kt = 0; kt < nt; kt++){
    int kv0 = kt * KVT;
    __syncthreads();                    // previous tile's LDS readers done
    *(short8*)(KsW)     = kr0;
    *(short8*)(KsW + 8) = kr1;
    *(short8*)(VsW)     = vr0;
    *(short8*)(VsW + 8) = vr1;
    if (kt + 1 < nt){                   // prefetch next tile (overlaps compute)
      int kvn = kv0 + KVT;
      kr0 = *(const short8*)(Krow + (size_t)kvn * DK);
      kr1 = *(const short8*)(Krow + (size_t)kvn * DK + 8);
      vr0 = *(const short8*)(Vrow + kvn);
      vr1 = *(const short8*)(Vrow + kvn + 8);
    }
    __syncthreads();                    // LDS tile ready

    if (kv0 <= qw + 31){
      floatx4 sc[2][4] = {};
      #pragma unroll
      for (int ni = 0; ni < 4; ni++){
        short8 bk0 = *(const short8*)&Ks[(ni * 16 + l15) * KPAD + quad * 8];
        short8 bk1 = *(const short8*)&Ks[(ni * 16 + l15) * KPAD + 32 + quad * 8];
        #pragma unroll
        for (int mi = 0; mi < 2; mi++){
          sc[mi][ni] = __builtin_amdgcn_mfma_f32_16x16x32_bf16(aq[mi][0], bk0, sc[mi][ni], 0, 0, 0);
          sc[mi][ni] = __builtin_amdgcn_mfma_f32_16x16x32_bf16(aq[mi][1], bk1, sc[mi][ni], 0, 0, 0);
        }
      }
      bool full = (kv0 + 63 <= qw);
      int kvb = kv0 + 4 * l15;          // actual kv of this lane's first column
      #pragma unroll
      for (int mi = 0; mi < 2; mi++){
        #pragma unroll
        for (int r = 0; r < 4; r++){
          int qg = qw + mi * 16 + quad * 4 + r;
          float v0 = sc[mi][0][r], v1 = sc[mi][1][r], v2 = sc[mi][2][r], v3 = sc[mi][3][r];
          if (!full){
            v0 = (kvb     > qg) ? -INFINITY : v0;
            v1 = (kvb + 1 > qg) ? -INFINITY : v1;
            v2 = (kvb + 2 > qg) ? -INFINITY : v2;
            v3 = (kvb + 3 > qg) ? -INFINITY : v3;
          }
          float p0 = fast_exp2(v0);
          float p1 = fast_exp2(v1);
          float p2 = fast_exp2(v2);
          float p3 = fast_exp2(v3);
          lsum[mi][r] += (p0 + p1) + (p2 + p3);
          uint2 u;
          u.x = pk_bf_trunc(p0, p1);
          u.y = pk_bf_trunc(p2, p3);
          *(uint2*)&Ps[wave][(mi * 16 + quad * 4 + r) * KPAD + 4 * l15] = u;
        }
      }
      asm volatile("s_waitcnt lgkmcnt(0)" ::: "memory");
      short8 ap[2][2];
      #pragma unroll
      for (int mi = 0; mi < 2; mi++){
        ap[mi][0] = *(const short8*)&Ps[wave][(mi * 16 + l15) * KPAD + quad * 8];
        ap[mi][1] = *(const short8*)&Ps[wave][(mi * 16 + l15) * KPAD + 32 + quad * 8];
      }
      #pragma unroll
      for (int dt = 0; dt < 4; dt++){
        short8 bv0 = *(const short8*)&Vs[(dt * 16 + l15) * KPAD + quad * 8];
        short8 bv1 = *(const short8*)&Vs[(dt * 16 + l15) * KPAD + 32 + quad * 8];
        #pragma unroll
        for (int mi = 0; mi < 2; mi++){
          o[mi][dt] = __builtin_amdgcn_mfma_f32_16x16x32_bf16(ap[mi][0], bv0, o[mi][dt], 0, 0, 0);
          o[mi][dt] = __builtin_amdgcn_mfma_f32_16x16x32_bf16(ap[mi][1], bv1, o[mi][dt], 0, 0, 0);
        }
      }
    }
  }

  float linv[2][4];
  #pragma unroll
  for (int mi = 0; mi < 2; mi++){
    #pragma unroll
    for (int r = 0; r < 4; r++){
      float rs = lsum[mi][r];
      rs += __shfl_xor(rs, 1);
      rs += __shfl_xor(rs, 2);
      rs += __shfl_xor(rs, 4);
      rs += __shfl_xor(rs, 8);
      linv[mi][r] = 1.0f / rs;
    }
  }

  int bq = bh >> 4, hq = bh & 15;
  #pragma unroll
  for (int mi = 0; mi < 2; mi++){
    #pragma unroll
    for (int dt = 0; dt < 4; dt++){
      #pragma unroll
      for (int r = 0; r < 4; r++){
        float val = o[mi][dt][r] * linv[mi][r];
        int s = qw + mi * 16 + quad * 4 + r;
        int d = dt * 16 + l15;
        Ao[(((size_t)bq * S_LEN + s) * NH + hq) * DK + d] = f2bf(val);
      }
    }
  }
}

extern "C" void kernel_launch(void* const* d_in, const int* in_sizes, int n_in,
                              void* d_out, int out_size, void* d_ws, size_t ws_size,
                              hipStream_t stream) {
  (void)in_sizes; (void)n_in; (void)out_size; (void)ws_size;
  const float* Wq = (const float*)d_in[0];
  const float* Wk = (const float*)d_in[1];
  const float* Wv = (const float*)d_in[2];
  const float* Wo = (const float*)d_in[3];
  const float* X  = (const float*)d_in[4];
  const int* pos  = (const int*)d_in[5];
  float* out = (float*)d_out;

  char* ws = (char*)d_ws;
  const size_t MB = 1024 * 1024;
  unsigned short* Xb  = (unsigned short*)(ws);             // 16 MB
  unsigned short* Wqb = (unsigned short*)(ws + 16 * MB);   // 2 MB
  unsigned short* Wkb = (unsigned short*)(ws + 18 * MB);
  unsigned short* Wvb = (unsigned short*)(ws + 20 * MB);
  unsigned short* Wob = (unsigned short*)(ws + 22 * MB);
  unsigned short* Qb  = (unsigned short*)(ws + 24 * MB);   // 16 MB
  unsigned short* Kb  = (unsigned short*)(ws + 40 * MB);
  unsigned short* Vb  = (unsigned short*)(ws + 56 * MB);   // transposed [bh][dk][S]
  unsigned short* Ab  = (unsigned short*)(ws + 72 * MB);

  cast_all<<<12288, 256, 0, stream>>>(X, Wq, Wk, Wv, Wo, Xb, Wqb, Wkb, Wvb, Wob);

  gemm_qkv<<<dim3(M_TOT/BM, DM/BN, 3), 512, 0, stream>>>(Xb, Wqb, Wkb, Wvb, pos, Qb, Kb, Vb);
  attn_kernel<<<dim3(64, S_LEN / QB), 256, 0, stream>>>(Qb, Kb, Vb, Ab);
  gemm_out<<<dim3(M_TOT/BM, DM/BN), 512, 0, stream>>>(Ab, Wob, out);
}

// Round 6
// 219.887 us; speedup vs baseline: 1.2301x; 1.1076x over previous
//
#include <hip/hip_runtime.h>
#include <stdint.h>
#include <math.h>

#define NH 16
#define DK 64
#define S_LEN 2048
#define BB 4
#define DM 1024
#define M_TOT (BB*S_LEN) // 8192
#define KVT 64
#define QB 128

// ---- GEMM geometry: 256x128 tile, BK=64, 8 waves (4M x 2N), triple-buffered LDS ----
#define BM 256
#define BN 128
#define BK 64
#define NTK (DM/BK)            // 16 K-tiles
#define LDS_A_BUF (BM*BK)      // 16384 ushort per buffer
#define LDS_B_BUF (BN*BK)      // 8192 ushort per buffer

typedef __attribute__((ext_vector_type(8))) short short8;
typedef __attribute__((ext_vector_type(4))) float floatx4;
typedef __attribute__((ext_vector_type(16))) float floatx16;

typedef const __attribute__((address_space(1))) void gas_t;
typedef __attribute__((address_space(3))) void las_t;

__device__ __forceinline__ void glds16(const void* g, void* l){
  __builtin_amdgcn_global_load_lds((gas_t*)g, (las_t*)l, 16, 0, 0);
}

// Sync primitives: inline-asm with "memory" clobber = compiler fence too.
#define VMCNT3() asm volatile("s_waitcnt vmcnt(3)" ::: "memory")
#define VMCNT6() asm volatile("s_waitcnt vmcnt(6)" ::: "memory")
#define VMCNT0() asm volatile("s_waitcnt vmcnt(0)" ::: "memory")
#define LGKM0()  do{ asm volatile("s_waitcnt lgkmcnt(0)" ::: "memory"); __builtin_amdgcn_sched_barrier(0); }while(0)
#define BARRIER() asm volatile("s_barrier" ::: "memory")
#define SCHEDB() __builtin_amdgcn_sched_barrier(0)

// v_permlane32_swap_b32 a, b: a's hi 32 lanes <-> b's lo 32 lanes.
// After: new_a = [a.lo | b.lo], new_b = [a.hi | b.hi].
#define PLSWAP(a, b) asm volatile("v_permlane32_swap_b32 %0, %1" : "+v"(a), "+v"(b))

__device__ __forceinline__ unsigned short f2bf(float f){
  unsigned int u = __float_as_uint(f);
  u += 0x7fffu + ((u >> 16) & 1u);
  return (unsigned short)(u >> 16);
}
// pack hi16(b):hi16(a) in one v_perm_b32 (truncation-rounded bf16 pair; a = low half)
__device__ __forceinline__ unsigned int pk_bf_trunc(float a, float b){
  return __builtin_amdgcn_perm(__float_as_uint(b), __float_as_uint(a), 0x07060302u);
}
__device__ __forceinline__ float fast_exp2(float x){
  return __builtin_amdgcn_exp2f(x);
}

// ---------------- cast fp32 -> bf16, all five tensors in ONE launch ----------------
__global__ void cast_all(const float* __restrict__ X,
                         const float* __restrict__ Wq, const float* __restrict__ Wk,
                         const float* __restrict__ Wv, const float* __restrict__ Wo,
                         unsigned short* __restrict__ Xb,
                         unsigned short* __restrict__ Wqb, unsigned short* __restrict__ Wkb,
                         unsigned short* __restrict__ Wvb, unsigned short* __restrict__ Wob)
{
  int b = blockIdx.x;
  const float* s;
  unsigned short* o;
  int base;
  if (b < 8192){ s = X; o = Xb; base = b; }
  else {
    int w = (b - 8192) >> 10;
    base = (b - 8192) & 1023;
    s = (w == 0) ? Wq : (w == 1) ? Wk : (w == 2) ? Wv : Wo;
    o = (w == 0) ? Wqb : (w == 1) ? Wkb : (w == 2) ? Wvb : Wob;
  }
  int i = base * 1024 + threadIdx.x * 4;
  float4 v = *(const float4*)(s + i);
  ushort4 u;
  u.x = f2bf(v.x); u.y = f2bf(v.y); u.z = f2bf(v.z); u.w = f2bf(v.w);
  *(ushort4*)(o + i) = u;
}

// Stage half of one K-tile (3 x glds16).  LDS dest lane-linear; source XOR-
// pre-swizzled (slot p of row r holds logical slot p^(r&7)). Conflict-free.
__device__ __forceinline__ void stage_part(const unsigned short* __restrict__ A,
                                           const unsigned short* __restrict__ Bm,
                                           int m0, int n0, int k0,
                                           unsigned short* As, unsigned short* Bs,
                                           int tid, int part)
{
  if (part == 0){
    #pragma unroll
    for (int j = 0; j < 2; j++){
      int c = j*512 + tid;
      int r = c >> 3;
      int sl = (c & 7) ^ (r & 7);
      glds16(&A[(size_t)(m0 + r)*DM + k0 + sl*8], (char*)As + (size_t)c*16);
    }
    int c = tid;
    int r = c >> 3;
    int sl = (c & 7) ^ (r & 7);
    glds16(&Bm[(size_t)(n0 + r)*DM + k0 + sl*8], (char*)Bs + (size_t)c*16);
  } else {
    #pragma unroll
    for (int j = 2; j < 4; j++){
      int c = j*512 + tid;
      int r = c >> 3;
      int sl = (c & 7) ^ (r & 7);
      glds16(&A[(size_t)(m0 + r)*DM + k0 + sl*8], (char*)As + (size_t)c*16);
    }
    int c = 512 + tid;
    int r = c >> 3;
    int sl = (c & 7) ^ (r & 7);
    glds16(&Bm[(size_t)(n0 + r)*DM + k0 + sl*8], (char*)Bs + (size_t)c*16);
  }
}

// Triple-buffered, counted-vmcnt, phase-interleaved K-loop with register
// software pipelining (round-3 proven form; k-chained MFMA order).
__device__ __forceinline__ void gemm_core(const unsigned short* __restrict__ A,
                                          const unsigned short* __restrict__ Bm,
                                          int m0, int n0, unsigned short* Ls,
                                          int tid, floatx4 (&acc)[4][4])
{
  unsigned short* AsB = Ls;                   // 3 x LDS_A_BUF
  unsigned short* BsB = Ls + 3*LDS_A_BUF;     // 3 x LDS_B_BUF
  int wave = tid >> 6, lane = tid & 63;
  int l15 = lane & 15, quad = lane >> 4;
  int wm = (wave >> 1) * 64, wn = (wave & 1) * 64;
  int s0 = quad ^ (l15 & 7);                  // swizzled slot for kk=0; kk=1 is s0^4

  short8 a01[2][2], a23[2][2], b[2][4][2];

  stage_part(A, Bm, m0, n0, 0,  AsB,             BsB,             tid, 0);
  stage_part(A, Bm, m0, n0, 0,  AsB,             BsB,             tid, 1);
  stage_part(A, Bm, m0, n0, BK, AsB + LDS_A_BUF, BsB + LDS_B_BUF, tid, 0);
  stage_part(A, Bm, m0, n0, BK, AsB + LDS_A_BUF, BsB + LDS_B_BUF, tid, 1);
  VMCNT6();
  BARRIER();
  #pragma unroll
  for (int mi = 0; mi < 2; mi++){
    const unsigned short* pr = AsB + (wm + mi*16 + l15)*BK;
    a01[mi][0] = *(const short8*)(pr + s0*8);
    a01[mi][1] = *(const short8*)(pr + (s0^4)*8);
  }
  #pragma unroll
  for (int ni = 0; ni < 4; ni++){
    const unsigned short* pr = BsB + (wn + ni*16 + l15)*BK;
    b[0][ni][0] = *(const short8*)(pr + s0*8);
    b[0][ni][1] = *(const short8*)(pr + (s0^4)*8);
  }

  #pragma unroll
  for (int t = 0; t < NTK; ++t){
    const int par = t & 1, nxt = par ^ 1;
    const unsigned short* Ab  = AsB + (t % 3)*LDS_A_BUF;
    const unsigned short* Abn = AsB + ((t+1) % 3)*LDS_A_BUF;
    const unsigned short* Bbn = BsB + ((t+1) % 3)*LDS_B_BUF;
    unsigned short* Ast = AsB + ((t+2) % 3)*LDS_A_BUF;
    unsigned short* Bst = BsB + ((t+2) % 3)*LDS_B_BUF;
    const int kst = (t + 2) * BK;

    // ---------------- phase A ----------------
    LGKM0();
    #pragma unroll
    for (int mi = 0; mi < 2; mi++){
      const unsigned short* pr = Ab + (wm + (2+mi)*16 + l15)*BK;
      a23[mi][0] = *(const short8*)(pr + s0*8);
      a23[mi][1] = *(const short8*)(pr + (s0^4)*8);
    }
    if (t + 2 < NTK) stage_part(A, Bm, m0, n0, kst, Ast, Bst, tid, 0);
    SCHEDB();
    __builtin_amdgcn_s_setprio(1);
    #pragma unroll
    for (int mi = 0; mi < 2; mi++)
      #pragma unroll
      for (int ni = 0; ni < 4; ni++){
        acc[mi][ni] = __builtin_amdgcn_mfma_f32_16x16x32_bf16(a01[mi][0], b[par][ni][0], acc[mi][ni], 0, 0, 0);
        acc[mi][ni] = __builtin_amdgcn_mfma_f32_16x16x32_bf16(a01[mi][1], b[par][ni][1], acc[mi][ni], 0, 0, 0);
      }
    __builtin_amdgcn_s_setprio(0);
    if (t + 2 < NTK)      { VMCNT3(); }
    else if (t + 1 < NTK) { VMCNT0(); }
    BARRIER();

    // ---------------- phase B ----------------
    LGKM0();
    if (t + 1 < NTK){
      #pragma unroll
      for (int mi = 0; mi < 2; mi++){
        const unsigned short* pr = Abn + (wm + mi*16 + l15)*BK;
        a01[mi][0] = *(const short8*)(pr + s0*8);
        a01[mi][1] = *(const short8*)(pr + (s0^4)*8);
      }
      #pragma unroll
      for (int ni = 0; ni < 4; ni++){
        const unsigned short* pr = Bbn + (wn + ni*16 + l15)*BK;
        b[nxt][ni][0] = *(const short8*)(pr + s0*8);
        b[nxt][ni][1] = *(const short8*)(pr + (s0^4)*8);
      }
    }
    if (t + 2 < NTK) stage_part(A, Bm, m0, n0, kst, Ast, Bst, tid, 1);
    SCHEDB();
    __builtin_amdgcn_s_setprio(1);
    #pragma unroll
    for (int mi = 0; mi < 2; mi++)
      #pragma unroll
      for (int ni = 0; ni < 4; ni++){
        acc[2+mi][ni] = __builtin_amdgcn_mfma_f32_16x16x32_bf16(a23[mi][0], b[par][ni][0], acc[2+mi][ni], 0, 0, 0);
        acc[2+mi][ni] = __builtin_amdgcn_mfma_f32_16x16x32_bf16(a23[mi][1], b[par][ni][1], acc[2+mi][ni], 0, 0, 0);
      }
    __builtin_amdgcn_s_setprio(0);
    if (t + 1 < NTK) BARRIER();
  }
}

// ---------------- QKV GEMM with fused RoPE (Q,K) and transposed-V epilogue ----------------
__global__ __launch_bounds__(512, 2) void gemm_qkv(
    const unsigned short* __restrict__ Xb,
    const unsigned short* __restrict__ Wq,
    const unsigned short* __restrict__ Wk,
    const unsigned short* __restrict__ Wv,
    const int* __restrict__ pos,
    unsigned short* __restrict__ Qo,
    unsigned short* __restrict__ Ko,
    unsigned short* __restrict__ VTo)
{
  __shared__ __align__(16) unsigned short Ls[3*LDS_A_BUF + 3*LDS_B_BUF];  // 144 KiB
  int m0 = blockIdx.x * BM;
  int n0 = blockIdx.y * BN;
  int z  = blockIdx.z;
  const unsigned short* Bmat = (z == 0) ? Wq : ((z == 1) ? Wk : Wv);
  unsigned short* Out = (z == 0) ? Qo : ((z == 1) ? Ko : VTo);

  int tid = threadIdx.x;
  floatx4 acc[4][4] = {};
  gemm_core(Xb, Bmat, m0, n0, Ls, tid, acc);

  int wave = tid >> 6, lane = tid & 63;
  int l15 = lane & 15, quad = lane >> 4;
  int wm = (wave >> 1) * 64, wn = (wave & 1) * 64;

  if (z == 2){
    #pragma unroll
    for (int mi = 0; mi < 4; mi++){
      int row0 = m0 + wm + mi * 16 + quad * 4;
      int bb2 = row0 >> 11, sQ = row0 & (S_LEN - 1);
      #pragma unroll
      for (int ni = 0; ni < 4; ni++){
        int col = n0 + wn + ni * 16 + l15;
        int h = col >> 6, d = col & 63;
        ushort4 u;
        u.x = f2bf(acc[mi][ni][0]); u.y = f2bf(acc[mi][ni][1]);
        u.z = f2bf(acc[mi][ni][2]); u.w = f2bf(acc[mi][ni][3]);
        *(ushort4*)&Out[(((size_t)bb2 * NH + h) * DK + d) * S_LEN + sQ] = u;
      }
    }
  } else {
    // RoPE via hardware v_sin/v_cos (revolutions): no libm calls -> no spills.
    const float SC = (z == 0) ? 0.180336879f : 1.0f;   // 0.125 * log2(e) for Q
    #pragma unroll
    for (int mi = 0; mi < 4; mi++){
      #pragma unroll
      for (int ni = 0; ni < 4; ni++){
        int col = n0 + wn + ni * 16 + l15;
        int h = col >> 6, d = col & 63;
        int fi = d >> 1, odd = d & 1;
        float invfrev = fast_exp2(-(float)fi * (13.2877123795494f / 32.0f)) * 0.15915494309f;
        #pragma unroll
        for (int r = 0; r < 4; r++){
          int row = m0 + wm + mi * 16 + quad * 4 + r;
          int bb2 = row >> 11, s = row & (S_LEN - 1);
          float p = (float)pos[s];
          float rev = p * invfrev;
          rev = rev - floorf(rev);
          float c  = __builtin_amdgcn_cosf(rev);
          float sn = __builtin_amdgcn_sinf(rev);
          float val = acc[mi][ni][r];
          float other = __shfl_xor(val, 1);
          float outv = odd ? (other * sn + val * c) : (val * c - other * sn);
          Out[(((size_t)bb2 * NH + h) * S_LEN + s) * DK + d] = f2bf(outv * SC);
        }
      }
    }
  }
}

// ---------------- Output projection GEMM: fp32 out ----------------
__global__ __launch_bounds__(512, 2) void gemm_out(
    const unsigned short* __restrict__ Ab,
    const unsigned short* __restrict__ Wo,
    float* __restrict__ Out)
{
  __shared__ __align__(16) unsigned short Ls[3*LDS_A_BUF + 3*LDS_B_BUF];
  int m0 = blockIdx.x * BM;
  int n0 = blockIdx.y * BN;

  int tid = threadIdx.x;
  floatx4 acc[4][4] = {};
  gemm_core(Ab, Wo, m0, n0, Ls, tid, acc);

  int wave = tid >> 6, lane = tid & 63;
  int l15 = lane & 15, quad = lane >> 4;
  int wm = (wave >> 1) * 64, wn = (wave & 1) * 64;

  #pragma unroll
  for (int mi = 0; mi < 4; mi++){
    #pragma unroll
    for (int ni = 0; ni < 4; ni++){
      #pragma unroll
      for (int r = 0; r < 4; r++){
        int row = m0 + wm + mi * 16 + quad * 4 + r;
        int col = n0 + wn + ni * 16 + l15;
        Out[(size_t)row * DM + col] = acc[mi][ni][r];
      }
    }
  }
}

// ---------------- Flash attention (causal), 32x32 swapped-operand, in-reg P ----
// Q pre-scaled by 0.125*log2(e) -> p = exp2(score); masked -> -inf -> 0.
// QK^T swapped: D = mfma_32x32x16(A=K, B=Q) => D col (lane&31) = q, D row
// (reg&3)+8*(reg>>2)+4*(lane>>5) = kv.  Each lane owns one q and 16 of 32 kv
// per subtile; the other 16 live in the partner half-wave.  P -> PV B-operand
// via T12: pack pairs (v_perm) then v_permlane32_swap pairing u[2i]<->u[2i+2]
// (one swap fills two output words).  No P LDS round-trip; single barrier per
// tile; K/V double-buffered XOR-swizzled [64][64] LDS (conflict-free).
// Heavy q-blocks dispatch FIRST (y reversed) so the drain tail is light.
__global__ __launch_bounds__(256, 3) void attn_kernel(
    const unsigned short* __restrict__ Qg,
    const unsigned short* __restrict__ Kg,
    const unsigned short* __restrict__ VTg,
    unsigned short* __restrict__ Ao)
{
  __shared__ __align__(16) unsigned short Ks[2][KVT * 64];   // [buf][kv][dk], slots XORed
  __shared__ __align__(16) unsigned short Vs[2][DK * 64];    // [buf][d][kv],  slots XORed

  int bh = blockIdx.x;
  int q0 = ((int)gridDim.y - 1 - (int)blockIdx.y) * QB;   // heavy-first
  int tid = threadIdx.x, wave = tid >> 6, lane = tid & 63;
  int l31 = lane & 31, hi = lane >> 5;
  int qw = q0 + wave * 32;
  int qg = qw + l31;                     // this lane's q row

  const unsigned short* Qb = Qg + (size_t)bh * S_LEN * DK;
  const unsigned short* Kb = Kg + (size_t)bh * S_LEN * DK;
  const unsigned short* Vb = VTg + (size_t)bh * DK * S_LEN;

  // Q B-operand frags: B[k][q]: lane holds Q[q=l31][kc*16 + hi*8 .. +7]
  short8 qf[4];
  #pragma unroll
  for (int kc = 0; kc < 4; kc++)
    qf[kc] = *(const short8*)&Qb[(size_t)qg * DK + kc * 16 + hi * 8];

  floatx16 oA = {0.f,0.f,0.f,0.f,0.f,0.f,0.f,0.f,0.f,0.f,0.f,0.f,0.f,0.f,0.f,0.f};
  floatx16 oB = {0.f,0.f,0.f,0.f,0.f,0.f,0.f,0.f,0.f,0.f,0.f,0.f,0.f,0.f,0.f,0.f};
  float lsum = 0.f;

  // per-lane LDS read element offsets for the 4 k-chunks (K and V share them)
  int e7 = l31 & 7;
  int eoff[4];
  #pragma unroll
  for (int kc = 0; kc < 4; kc++)
    eoff[kc] = l31 * 64 + (((kc * 2 + hi) ^ e7) * 8);

  // staging: thread (srow, sj) covers row srow, 16B slots 2sj, 2sj+1 (swizzled)
  int srow = tid >> 2, sj = tid & 3;
  const unsigned short* Krow = Kb + (size_t)srow * DK + sj * 16;
  const unsigned short* Vrow = Vb + (size_t)srow * S_LEN + sj * 16;
  int ws0 = (((2 * sj)     ^ (srow & 7)) * 8) + srow * 64;
  int ws1 = (((2 * sj + 1) ^ (srow & 7)) * 8) + srow * 64;

  int nt = q0 / KVT + 2;

  // prefetch tile 0
  short8 kr0 = *(const short8*)(Krow);
  short8 kr1 = *(const short8*)(Krow + 8);
  short8 vr0 = *(const short8*)(Vrow);
  short8 vr1 = *(const short8*)(Vrow + 8);

  for (int kt = 0; kt < nt; kt++){
    int kv0 = kt * KVT;
    int p = kt & 1;
    *(short8*)&Ks[p][ws0] = kr0;
    *(short8*)&Ks[p][ws1] = kr1;
    *(short8*)&Vs[p][ws0] = vr0;
    *(short8*)&Vs[p][ws1] = vr1;
    if (kt + 1 < nt){                    // prefetch next tile (hides under compute)
      int kvn = kv0 + KVT;
      kr0 = *(const short8*)(Krow + (size_t)kvn * DK);
      kr1 = *(const short8*)(Krow + (size_t)kvn * DK + 8);
      vr0 = *(const short8*)(Vrow + kvn);
      vr1 = *(const short8*)(Vrow + kvn + 8);
    }
    LGKM0();                             // own ds_writes done
    BARRIER();                           // tile published; one barrier per tile

    #pragma unroll
    for (int sub = 0; sub < 2; sub++){
      int kvs = kv0 + sub * 32;
      if (kvs <= qw + 31){               // wave-uniform
        bool subfull = (kvs + 31 <= qw);
        // ---- QK^T swapped ----
        floatx16 s16 = {0.f,0.f,0.f,0.f,0.f,0.f,0.f,0.f,0.f,0.f,0.f,0.f,0.f,0.f,0.f,0.f};
        #pragma unroll
        for (int kc = 0; kc < 4; kc++){
          short8 kf = *(const short8*)&Ks[p][sub * 2048 + eoff[kc]];
          s16 = __builtin_amdgcn_mfma_f32_32x32x16_bf16(kf, qf[kc], s16, 0, 0, 0);
        }
        // ---- softmax (no-max): mask, exp2, pack ----
        unsigned int u[8];
        float ls = 0.f;
        #pragma unroll
        for (int j = 0; j < 8; j++){
          int row0 = ((2*j) & 3) + 8 * ((2*j) >> 2) + 4 * hi;  // kv row of reg 2j
          float v0 = s16[2*j], v1 = s16[2*j+1];
          if (!subfull){
            v0 = (kvs + row0     > qg) ? -INFINITY : v0;
            v1 = (kvs + row0 + 1 > qg) ? -INFINITY : v1;
          }
          float p0 = fast_exp2(v0);
          float p1 = fast_exp2(v1);
          ls += p0 + p1;
          u[j] = pk_bf_trunc(p0, p1);
        }
        lsum += ls;
        // ---- half-wave exchange: u[2i] <-> u[2i+2] ----
        PLSWAP(u[0], u[2]); PLSWAP(u[1], u[3]);
        PLSWAP(u[4], u[6]); PLSWAP(u[5], u[7]);
        union { unsigned int w[4]; short8 v; } c0, c1;
        c0.w[0] = u[0]; c0.w[1] = u[1]; c0.w[2] = u[2]; c0.w[3] = u[3];
        c1.w[0] = u[4]; c1.w[1] = u[5]; c1.w[2] = u[6]; c1.w[3] = u[7];
        // ---- PV for this sub: kv chunks sub*2, sub*2+1 ----
        short8 vf0 = *(const short8*)&Vs[p][eoff[sub*2]];
        short8 vf1 = *(const short8*)&Vs[p][eoff[sub*2+1]];
        short8 vf2 = *(const short8*)&Vs[p][2048 + eoff[sub*2]];
        short8 vf3 = *(const short8*)&Vs[p][2048 + eoff[sub*2+1]];
        oA = __builtin_amdgcn_mfma_f32_32x32x16_bf16(vf0, c0.v, oA, 0, 0, 0);
        oA = __builtin_amdgcn_mfma_f32_32x32x16_bf16(vf1, c1.v, oA, 0, 0, 0);
        oB = __builtin_amdgcn_mfma_f32_32x32x16_bf16(vf2, c0.v, oB, 0, 0, 0);
        oB = __builtin_amdgcn_mfma_f32_32x32x16_bf16(vf3, c1.v, oB, 0, 0, 0);
      }
    }
  }

  // each half-wave summed 32 of 64 kv for its q; combine
  float rs = lsum + __shfl_xor(lsum, 32);
  float linv = 1.0f / rs;

  int bq = bh >> 4, hq = bh & 15;
  size_t obase = (((size_t)bq * S_LEN + qg) * NH + hq) * DK;
  #pragma unroll
  for (int g = 0; g < 4; g++){
    int d0 = 8 * g + 4 * hi;
    ushort4 ua, ub;
    ua.x = f2bf(oA[4*g+0] * linv); ua.y = f2bf(oA[4*g+1] * linv);
    ua.z = f2bf(oA[4*g+2] * linv); ua.w = f2bf(oA[4*g+3] * linv);
    ub.x = f2bf(oB[4*g+0] * linv); ub.y = f2bf(oB[4*g+1] * linv);
    ub.z = f2bf(oB[4*g+2] * linv); ub.w = f2bf(oB[4*g+3] * linv);
    *(ushort4*)&Ao[obase + d0]      = ua;
    *(ushort4*)&Ao[obase + 32 + d0] = ub;
  }
}

extern "C" void kernel_launch(void* const* d_in, const int* in_sizes, int n_in,
                              void* d_out, int out_size, void* d_ws, size_t ws_size,
                              hipStream_t stream) {
  (void)in_sizes; (void)n_in; (void)out_size; (void)ws_size;
  const float* Wq = (const float*)d_in[0];
  const float* Wk = (const float*)d_in[1];
  const float* Wv = (const float*)d_in[2];
  const float* Wo = (const float*)d_in[3];
  const float* X  = (const float*)d_in[4];
  const int* pos  = (const int*)d_in[5];
  float* out = (float*)d_out;

  char* ws = (char*)d_ws;
  const size_t MB = 1024 * 1024;
  unsigned short* Xb  = (unsigned short*)(ws);             // 16 MB
  unsigned short* Wqb = (unsigned short*)(ws + 16 * MB);   // 2 MB
  unsigned short* Wkb = (unsigned short*)(ws + 18 * MB);
  unsigned short* Wvb = (unsigned short*)(ws + 20 * MB);
  unsigned short* Wob = (unsigned short*)(ws + 22 * MB);
  unsigned short* Qb  = (unsigned short*)(ws + 24 * MB);   // 16 MB
  unsigned short* Kb  = (unsigned short*)(ws + 40 * MB);
  unsigned short* Vb  = (unsigned short*)(ws + 56 * MB);   // transposed [bh][dk][S]
  unsigned short* Ab  = (unsigned short*)(ws + 72 * MB);

  cast_all<<<12288, 256, 0, stream>>>(X, Wq, Wk, Wv, Wo, Xb, Wqb, Wkb, Wvb, Wob);

  gemm_qkv<<<dim3(M_TOT/BM, DM/BN, 3), 512, 0, stream>>>(Xb, Wqb, Wkb, Wvb, pos, Qb, Kb, Vb);
  attn_kernel<<<dim3(64, S_LEN / QB), 256, 0, stream>>>(Qb, Kb, Vb, Ab);
  gemm_out<<<dim3(M_TOT/BM, DM/BN), 512, 0, stream>>>(Ab, Wob, out);
}